// Round 6
// baseline (377.138 us; speedup 1.0000x reference)
//
#include <hip/hip_runtime.h>
#include <hip/hip_bf16.h>
#include <math.h>

// ---------- types ----------
typedef __attribute__((ext_vector_type(8))) short short8;    // 8 x bf16
typedef __attribute__((ext_vector_type(4))) float f32x4;
typedef __attribute__((ext_vector_type(16))) float f32x16;

// B=16, H=W=64 -> N=4096 tokens/batch, C=256, M = B*N = 65536
#define NTOK 4096
#define CDIM 256
#define MROWS 65536

static __device__ __forceinline__ unsigned short f2bf(float f) {
    union { float f; unsigned int u; } v; v.f = f;
    unsigned int u = v.u;
    return (unsigned short)((u + 0x7fffu + ((u >> 16) & 1u)) >> 16);  // RNE
}

static __device__ __forceinline__ unsigned cvt_pk_bf16(float lo, float hi) {
    unsigned r;
    asm("v_cvt_pk_bf16_f32 %0, %1, %2" : "=v"(r) : "v"(lo), "v"(hi));
    return r;
}

static __device__ __forceinline__ f32x4 mfma32(short8 a, short8 b, f32x4 c) {
    return __builtin_amdgcn_mfma_f32_16x16x32_bf16(a, b, c, 0, 0, 0);
}

static __device__ __forceinline__ f32x16 mfma32x32(short8 a, short8 b, f32x16 c) {
    return __builtin_amdgcn_mfma_f32_32x32x16_bf16(a, b, c, 0, 0, 0);
}

// async global -> LDS DMA, 16B per lane (dst = wave-uniform base + lane*16)
static __device__ __forceinline__ void ldsdma16(char* l, const char* g) {
    __builtin_amdgcn_global_load_lds(
        (const __attribute__((address_space(1))) unsigned int*)g,
        (__attribute__((address_space(3))) unsigned int*)l,
        16, 0, 0);
}

// ---------- kernel 1: transpose + convert weights to bf16 ----------
// wt_all[z][c_out][c_in] = w_z[c_in][c_out]; z=0 (Wq) folds in the 1/16 scale.
__global__ __launch_bounds__(256) void prep_w_kernel(
    const float* __restrict__ wq, const float* __restrict__ wk,
    const float* __restrict__ wv, const float* __restrict__ wp,
    unsigned short* __restrict__ wt_all)
{
    const int o = blockIdx.x;      // c_out
    const int t = threadIdx.x;     // c_in
    const int z = blockIdx.y;
    const float* w = (z == 0) ? wq : (z == 1) ? wk : (z == 2) ? wv : wp;
    const float s = (z == 0) ? 0.0625f : 1.0f;
    wt_all[z * 65536 + o * 256 + t] = f2bf(w[t * 256 + o] * s);
}

// ---------- kernel 2: QKV projections (weights streamed through LDS) ----------
__global__ __launch_bounds__(256) void qkv_kernel(
    const float* __restrict__ x,
    const unsigned short* __restrict__ wt_all,
    const float* __restrict__ bq, const float* __restrict__ bk,
    const float* __restrict__ bv,
    unsigned short* __restrict__ q_ws, unsigned short* __restrict__ k_img,
    unsigned short* __restrict__ v_img)
{
    __shared__ unsigned short xs[64 * 256];   // 32 KB: X tile, then result staging
    __shared__ char wchunk[32768];            // 64 c_out x 512B (swizzled 16B slots)
    const int t = threadIdx.x;
    const long m0 = (long)blockIdx.x * 64;
    const int bb = (int)(m0 >> 12);
    const int tile = (int)((m0 & 4095) >> 6);
    const long img_base = ((long)bb * 64 + tile) * 32768;  // bytes

    const int wave = t >> 6, lane = t & 63;
    const int lr = lane & 15, lh = lane >> 4;

    // weight chunk staging: global -> regs -> swizzled LDS
    short8 wreg[8];
    auto wload = [&](int j) {   // chunk j in 0..11 (z = j>>2, cc = j&3)
        const char* src = (const char*)wt_all + (long)j * 32768 + t * 16;
        #pragma unroll
        for (int i = 0; i < 8; ++i)
            wreg[i] = *reinterpret_cast<const short8*>(src + i * 4096);
    };
    auto wstore = [&]() {
        #pragma unroll
        for (int i = 0; i < 8; ++i) {
            int g = i * 4096 + t * 16;
            int row = g >> 9, slot = (g >> 4) & 31;
            *reinterpret_cast<short8*>(
                wchunk + row * 512 + ((slot ^ (row & 7)) * 16)) = wreg[i];
        }
    };

    wload(0);

    // stage X tile (fp32 -> bf16) into LDS
    #pragma unroll
    for (int i = 0; i < 16; ++i) {
        int idx = i * 256 + t;
        int row = idx >> 6;
        int c4 = (idx & 63) << 2;
        float4 v = *reinterpret_cast<const float4*>(x + (m0 + row) * CDIM + c4);
        ushort4 pk;
        pk.x = f2bf(v.x); pk.y = f2bf(v.y); pk.z = f2bf(v.z); pk.w = f2bf(v.w);
        *reinterpret_cast<ushort4*>(&xs[row * 256 + c4]) = pk;
    }
    __syncthreads();

    short8 a_frag[8];
    #pragma unroll
    for (int kk = 0; kk < 8; ++kk)
        a_frag[kk] = *reinterpret_cast<const short8*>(
            &xs[(wave * 16 + lr) * 256 + kk * 32 + lh * 8]);

    wstore();
    __syncthreads();
    wload(1);

    for (int j = 0; j < 12; ++j) {
        const int z = j >> 2, cc = j & 3;

        f32x4 acc[4];
        #pragma unroll
        for (int cb = 0; cb < 4; ++cb) acc[cb] = (f32x4)(0.0f);

        __builtin_amdgcn_s_setprio(1);
        #pragma unroll
        for (int kk = 0; kk < 8; ++kk) {
            #pragma unroll
            for (int cb = 0; cb < 4; ++cb) {
                short8 b_frag = *reinterpret_cast<const short8*>(
                    wchunk + (cb * 16 + lr) * 512 + (((kk * 4 + lh) ^ (lr & 7)) * 16));
                acc[cb] = mfma32(a_frag[kk], b_frag, acc[cb]);
            }
        }
        __builtin_amdgcn_s_setprio(0);

        if (z < 2) {
            const float* bias = (z == 0) ? bq : bk;
            const float bs = (z == 0) ? 0.0625f : 1.0f;
            #pragma unroll
            for (int cb = 0; cb < 4; ++cb) {
                int c = cc * 64 + cb * 16 + lr;
                float bb_ = bias[c] * bs;
                #pragma unroll
                for (int r = 0; r < 4; ++r)
                    xs[(wave * 16 + lh * 4 + r) * 256 + c] = f2bf(acc[cb][r] + bb_);
            }
        } else {
            char* xc = (char*)xs;
            #pragma unroll
            for (int cb = 0; cb < 4; ++cb) {
                int c = cc * 64 + cb * 16 + lr;
                float bb_ = bv[c];
                #pragma unroll
                for (int r = 0; r < 4; ++r) {
                    int n = wave * 16 + lh * 4 + r;
                    *reinterpret_cast<unsigned short*>(
                        xc + c * 128 + (((n >> 3) ^ (c & 7)) * 16) + (n & 7) * 2)
                        = f2bf(acc[cb][r] + bb_);
                }
            }
        }
        __syncthreads();

        if (cc == 3) {
            if (z == 0) {
                char* dst = (char*)q_ws + m0 * 512;
                const char* src = (const char*)xs;
                #pragma unroll
                for (int i = 0; i < 8; ++i) {
                    int g = i * 4096 + t * 16;
                    *reinterpret_cast<short8*>(dst + g) =
                        *reinterpret_cast<const short8*>(src + g);
                }
            } else if (z == 1) {
                char* dst = (char*)k_img + img_base;
                #pragma unroll
                for (int i = 0; i < 8; ++i) {
                    int g = i * 4096 + t * 16;
                    int row = g >> 9, sp = (g >> 4) & 31;
                    int s = sp ^ (row & 7);
                    *reinterpret_cast<short8*>(dst + g) =
                        *reinterpret_cast<const short8*>(&xs[row * 256 + s * 8]);
                }
            } else {
                char* dst = (char*)v_img + img_base;
                const char* src = (const char*)xs;
                #pragma unroll
                for (int i = 0; i < 8; ++i) {
                    int g = i * 4096 + t * 16;
                    *reinterpret_cast<short8*>(dst + g) =
                        *reinterpret_cast<const short8*>(src + g);
                }
            }
        }

        if (j < 11) wstore();
        if (j < 10) wload(j + 2);
        __syncthreads();
    }
}

// ---------- kernel 3: fused flash attention (32x32 MFMA) + projection + residual ----------
// 256 blocks, 8 waves x 32 q rows. Swapped QK^T via mfma_32x32x16 (lane owns one
// q column), in-register softmax (T12: cvt_pk + shfl_xor(32) P redistribution),
// full-rate 32x32 PV, global_load_lds double-buffered K/V staging.
__global__ __launch_bounds__(512, 2) void attn_kernel(
    const unsigned short* __restrict__ q_ws,
    const unsigned short* __restrict__ k_img,
    const unsigned short* __restrict__ v_img,
    const unsigned short* __restrict__ wpt,
    const float* __restrict__ bp,
    const float* __restrict__ x,
    float* __restrict__ out)
{
    extern __shared__ char smem[];
    char* ksb = smem;             // 2 x 32KB K tiles [64 k][512B], slot ^= row&7
    char* vsb = smem + 65536;     // 2 x 32KB V tiles [256 c][128B], slot ^= c&7
    const int t = threadIdx.x;
    const int wave = t >> 6, lane = t & 63;
    const int q32 = lane & 31;    // lane's q column (and K/V row index)
    const int u   = lane >> 5;
    const int lr = lane & 15, lh = lane >> 4;   // for 16x16 proj epilogue

    // XCD-aware mapping: batch b's 16 blocks all live on XCD b>>1
    const int bid = blockIdx.x;
    const int xcd = bid & 7, ii = bid >> 3;
    const int b = (xcd << 1) | (ii & 1);
    const int qc = ii >> 1;
    const long qbase = (long)b * NTOK + qc * 256 + wave * 32;

    const char* kg = (const char*)k_img + ((long)b * 64) * 32768;
    const char* vg = (const char*)v_img + ((long)b * 64) * 32768;

    // resident Q (B-operand): qf[kk] = Q[qbase+q32][kk*16 + u*8 .. +8], scale folded
    short8 qf[16];
    #pragma unroll
    for (int kk = 0; kk < 16; ++kk)
        qf[kk] = *reinterpret_cast<const short8*>(
            &q_ws[(qbase + q32) * 256 + kk * 16 + u * 8]);

    // acc[cb]: O^T[c = cb*32 + (r&3)+8*(r>>2)+4u][q32]
    f32x16 acc[8];
    #pragma unroll
    for (int cb = 0; cb < 8; ++cb) acc[cb] = (f32x16)(0.0f);
    float m_run = -INFINITY, l_run = 0.f;

    auto stage = [&](int nb, int tt) {
        const char* ks = kg + (long)tt * 32768 + wave * 4096 + lane * 16;
        char* kd = ksb + nb * 32768 + wave * 4096;
        #pragma unroll
        for (int i = 0; i < 4; ++i) ldsdma16(kd + i * 1024, ks + i * 1024);
        const char* vs = vg + (long)tt * 32768 + wave * 4096 + lane * 16;
        char* vd = vsb + nb * 32768 + wave * 4096;
        #pragma unroll
        for (int i = 0; i < 4; ++i) ldsdma16(vd + i * 1024, vs + i * 1024);
    };

    stage(0, 0);
    __syncthreads();

    for (int tt = 0; tt < 64; ++tt) {
        const int buf = tt & 1;
        if (tt < 63) stage(buf ^ 1, tt + 1);   // issue early; barrier drains it
        const char* kb = ksb + buf * 32768;
        const char* vb = vsb + buf * 32768;

        #pragma unroll
        for (int h = 0; h < 2; ++h) {
            // ---- QK^T: S^T[32 k][32 q] in one f32x16 ----
            f32x16 s = (f32x16)(0.0f);
            __builtin_amdgcn_s_setprio(1);
            #pragma unroll
            for (int kk = 0; kk < 16; ++kk) {
                short8 kf = *reinterpret_cast<const short8*>(
                    kb + (h * 32 + q32) * 512 + (((kk * 2 + u) ^ (q32 & 7)) * 16));
                s = mfma32x32(kf, qf[kk], s);
            }
            __builtin_amdgcn_s_setprio(0);

            // ---- in-register online softmax (lane owns q; 16 k vals + partner) ----
            float mt = fmaxf(fmaxf(fmaxf(s[0], s[1]), fmaxf(s[2], s[3])),
                             fmaxf(fmaxf(s[4], s[5]), fmaxf(s[6], s[7])));
            mt = fmaxf(mt, fmaxf(fmaxf(fmaxf(s[8], s[9]), fmaxf(s[10], s[11])),
                                 fmaxf(fmaxf(s[12], s[13]), fmaxf(s[14], s[15]))));
            mt = fmaxf(mt, __shfl_xor(mt, 32));
            if (!__all(mt <= m_run + 8.0f)) {     // defer-max (T13)
                float mn = fmaxf(m_run, mt);
                float a = __expf(m_run - mn);
                l_run *= a;
                #pragma unroll
                for (int cb = 0; cb < 8; ++cb)
                    #pragma unroll
                    for (int r = 0; r < 16; ++r) acc[cb][r] *= a;
                m_run = mn;
            }
            unsigned plo[4], phi[4];
            float rs = 0.f;
            #pragma unroll
            for (int m = 0; m < 4; ++m) {
                float e0 = __expf(s[4*m+0] - m_run);
                float e1 = __expf(s[4*m+1] - m_run);
                float e2 = __expf(s[4*m+2] - m_run);
                float e3 = __expf(s[4*m+3] - m_run);
                rs += (e0 + e1) + (e2 + e3);
                plo[m] = cvt_pk_bf16(e0, e1);   // k = 8m+4u+0,1
                phi[m] = cvt_pk_bf16(e2, e3);   // k = 8m+4u+2,3
            }
            rs += __shfl_xor(rs, 32);
            l_run += rs;

            // ---- PV: acc[c][q] += V^T[c][k16] @ P^T[k16][q], two K=16 steps ----
            #pragma unroll
            for (int tp = 0; tp < 2; ++tp) {
                // B-frag k = 16*tp + 8u + j. Lane (q,u) needs P_lo/P_hi[2tp+u]
                // from BOTH 32-lane halves (own + partner via shfl_xor 32).
                unsigned xl = plo[2*tp], yl = plo[2*tp+1];
                unsigned xh = phi[2*tp], yh = phi[2*tp+1];
                unsigned xls = __shfl_xor(xl, 32);
                unsigned yls = __shfl_xor(yl, 32);
                unsigned xhs = __shfl_xor(xh, 32);
                unsigned yhs = __shfl_xor(yh, 32);
                union { unsigned w[4]; short8 v; } pf;
                pf.w[0] = u ? yls : xl;    // k pair (16tp+8u+0,1)  from u_s=0
                pf.w[1] = u ? yhs : xh;    // k pair (+2,+3)        from u_s=0
                pf.w[2] = u ? yl  : xls;   // k pair (+4,+5)        from u_s=1
                pf.w[3] = u ? yh  : xhs;   // k pair (+6,+7)        from u_s=1
                __builtin_amdgcn_s_setprio(1);
                #pragma unroll
                for (int cb = 0; cb < 8; ++cb) {
                    int c = cb * 32 + q32;
                    short8 vf = *reinterpret_cast<const short8*>(
                        vb + c * 128 + (((h * 4 + 2 * tp + u) ^ (c & 7)) * 16));
                    acc[cb] = mfma32x32(vf, pf.v, acc[cb]);
                }
                __builtin_amdgcn_s_setprio(0);
            }
        }
        __syncthreads();   // drains DMA for tile tt+1; K/V readers done
    }

    // ---- epilogue: O^T -> per-wave LDS transpose (swizzled, paired b32 writes) ----
    __syncthreads();   // all waves done with ksb/vsb before overwriting with ot
    float inv = 1.0f / l_run;
    char* ot = smem + wave * 16384;   // [32 q][512B], slot ^= q&7
    #pragma unroll
    for (int cb = 0; cb < 8; ++cb) {
        #pragma unroll
        for (int i = 0; i < 8; ++i) {
            int c = cb * 32 + ((2 * i) & 3) + 8 * (i >> 1) + 4 * u;
            unsigned w = cvt_pk_bf16(acc[cb][2*i] * inv, acc[cb][2*i+1] * inv);
            *reinterpret_cast<unsigned*>(
                ot + q32 * 512 + (((c >> 3) ^ (q32 & 7)) * 16) + (c & 7) * 2) = w;
        }
    }

    // ---- fused projection: OUT = O @ Wp + bp + x (16x16x32, per-wave ot) ----
    f32x4 po[2][16];
    #pragma unroll
    for (int qb = 0; qb < 2; ++qb)
        #pragma unroll
        for (int cb = 0; cb < 16; ++cb) po[qb][cb] = (f32x4)(0.0f);

    for (int kk = 0; kk < 8; ++kk) {
        int slot = (kk * 4 + lh);
        short8 a0 = *reinterpret_cast<const short8*>(
            ot + (0 * 16 + lr) * 512 + ((slot ^ (lr & 7)) * 16));
        short8 a1 = *reinterpret_cast<const short8*>(
            ot + (1 * 16 + lr) * 512 + ((slot ^ (lr & 7)) * 16));
        #pragma unroll
        for (int cb = 0; cb < 16; ++cb) {
            short8 bf_ = *reinterpret_cast<const short8*>(
                &wpt[(cb * 16 + lr) * 256 + kk * 32 + lh * 8]);
            po[0][cb] = mfma32(a0, bf_, po[0][cb]);
            po[1][cb] = mfma32(a1, bf_, po[1][cb]);
        }
    }

    #pragma unroll
    for (int qb = 0; qb < 2; ++qb) {
        #pragma unroll
        for (int cb = 0; cb < 16; ++cb) {
            int c = cb * 16 + lr;
            float bias = bp[c];
            #pragma unroll
            for (int r = 0; r < 4; ++r) {
                long row = qbase + qb * 16 + lh * 4 + r;
                out[row * 256 + c] = po[qb][cb][r] + bias + x[row * 256 + c];
            }
        }
    }
}

extern "C" void kernel_launch(void* const* d_in, const int* in_sizes, int n_in,
                              void* d_out, int out_size, void* d_ws, size_t ws_size,
                              hipStream_t stream) {
    const float* x  = (const float*)d_in[0];
    const float* wq = (const float*)d_in[1];
    const float* bq = (const float*)d_in[2];
    const float* wk = (const float*)d_in[3];
    const float* bk = (const float*)d_in[4];
    const float* wv = (const float*)d_in[5];
    const float* bv = (const float*)d_in[6];
    const float* wp = (const float*)d_in[7];
    const float* bp = (const float*)d_in[8];
    float* out = (float*)d_out;

    char* ws = (char*)d_ws;
    unsigned short* wt_all = (unsigned short*)ws;               // 512 KiB
    unsigned short* q_ws   = (unsigned short*)(ws + 524288);    // 32 MiB
    unsigned short* k_img  = q_ws + (size_t)MROWS * CDIM;       // 32 MiB
    unsigned short* v_img  = k_img + (size_t)MROWS * CDIM;      // 32 MiB

    prep_w_kernel<<<dim3(256, 4), 256, 0, stream>>>(wq, wk, wv, wp, wt_all);
    qkv_kernel<<<dim3(MROWS / 64), 256, 0, stream>>>(x, wt_all, bq, bk, bv,
                                                     q_ws, k_img, v_img);
    hipFuncSetAttribute((const void*)attn_kernel,
                        hipFuncAttributeMaxDynamicSharedMemorySize, 131072);
    attn_kernel<<<dim3(256), 512, 131072, stream>>>(q_ws, k_img, v_img,
                                                    wt_all + 3 * 65536, bp, x, out);
}

// Round 7
// 375.189 us; speedup vs baseline: 1.0052x; 1.0052x over previous
//
#include <hip/hip_runtime.h>
#include <hip/hip_bf16.h>
#include <math.h>

// ---------- types ----------
typedef __attribute__((ext_vector_type(8))) short short8;    // 8 x bf16
typedef __attribute__((ext_vector_type(4))) float f32x4;
typedef __attribute__((ext_vector_type(16))) float f32x16;

// B=16, H=W=64 -> N=4096 tokens/batch, C=256, M = B*N = 65536
#define NTOK 4096
#define CDIM 256
#define MROWS 65536

static __device__ __forceinline__ unsigned short f2bf(float f) {
    union { float f; unsigned int u; } v; v.f = f;
    unsigned int u = v.u;
    return (unsigned short)((u + 0x7fffu + ((u >> 16) & 1u)) >> 16);  // RNE
}

static __device__ __forceinline__ unsigned cvt_pk_bf16(float lo, float hi) {
    unsigned r;
    asm("v_cvt_pk_bf16_f32 %0, %1, %2" : "=v"(r) : "v"(lo), "v"(hi));
    return r;
}

static __device__ __forceinline__ f32x4 mfma32(short8 a, short8 b, f32x4 c) {
    return __builtin_amdgcn_mfma_f32_16x16x32_bf16(a, b, c, 0, 0, 0);
}

static __device__ __forceinline__ f32x16 mfma32x32(short8 a, short8 b, f32x16 c) {
    return __builtin_amdgcn_mfma_f32_32x32x16_bf16(a, b, c, 0, 0, 0);
}

// async global -> LDS DMA, 16B per lane (dst = wave-uniform base + lane*16)
static __device__ __forceinline__ void ldsdma16(char* l, const char* g) {
    __builtin_amdgcn_global_load_lds(
        (const __attribute__((address_space(1))) unsigned int*)g,
        (__attribute__((address_space(3))) unsigned int*)l,
        16, 0, 0);
}

// ---------- kernel 1: transpose + convert weights to bf16 ----------
// wt_all[z][c_out][c_in] = w_z[c_in][c_out]; z=0 (Wq) folds in the 1/16 scale.
__global__ __launch_bounds__(256) void prep_w_kernel(
    const float* __restrict__ wq, const float* __restrict__ wk,
    const float* __restrict__ wv, const float* __restrict__ wp,
    unsigned short* __restrict__ wt_all)
{
    const int o = blockIdx.x;      // c_out
    const int t = threadIdx.x;     // c_in
    const int z = blockIdx.y;
    const float* w = (z == 0) ? wq : (z == 1) ? wk : (z == 2) ? wv : wp;
    const float s = (z == 0) ? 0.0625f : 1.0f;
    wt_all[z * 65536 + o * 256 + t] = f2bf(w[t * 256 + o] * s);
}

// ---------- kernel 2: QKV projections (weights streamed through LDS) ----------
__global__ __launch_bounds__(256) void qkv_kernel(
    const float* __restrict__ x,
    const unsigned short* __restrict__ wt_all,
    const float* __restrict__ bq, const float* __restrict__ bk,
    const float* __restrict__ bv,
    unsigned short* __restrict__ q_ws, unsigned short* __restrict__ k_img,
    unsigned short* __restrict__ v_img)
{
    __shared__ unsigned short xs[64 * 256];   // 32 KB: X tile, then result staging
    __shared__ char wchunk[32768];            // 64 c_out x 512B (swizzled 16B slots)
    const int t = threadIdx.x;
    const long m0 = (long)blockIdx.x * 64;
    const int bb = (int)(m0 >> 12);
    const int tile = (int)((m0 & 4095) >> 6);
    const long img_base = ((long)bb * 64 + tile) * 32768;  // bytes

    const int wave = t >> 6, lane = t & 63;
    const int lr = lane & 15, lh = lane >> 4;

    // weight chunk staging: global -> regs -> swizzled LDS
    short8 wreg[8];
    auto wload = [&](int j) {   // chunk j in 0..11 (z = j>>2, cc = j&3)
        const char* src = (const char*)wt_all + (long)j * 32768 + t * 16;
        #pragma unroll
        for (int i = 0; i < 8; ++i)
            wreg[i] = *reinterpret_cast<const short8*>(src + i * 4096);
    };
    auto wstore = [&]() {
        #pragma unroll
        for (int i = 0; i < 8; ++i) {
            int g = i * 4096 + t * 16;
            int row = g >> 9, slot = (g >> 4) & 31;
            *reinterpret_cast<short8*>(
                wchunk + row * 512 + ((slot ^ (row & 7)) * 16)) = wreg[i];
        }
    };

    wload(0);

    // stage X tile (fp32 -> bf16) into LDS
    #pragma unroll
    for (int i = 0; i < 16; ++i) {
        int idx = i * 256 + t;
        int row = idx >> 6;
        int c4 = (idx & 63) << 2;
        float4 v = *reinterpret_cast<const float4*>(x + (m0 + row) * CDIM + c4);
        ushort4 pk;
        pk.x = f2bf(v.x); pk.y = f2bf(v.y); pk.z = f2bf(v.z); pk.w = f2bf(v.w);
        *reinterpret_cast<ushort4*>(&xs[row * 256 + c4]) = pk;
    }
    __syncthreads();

    short8 a_frag[8];
    #pragma unroll
    for (int kk = 0; kk < 8; ++kk)
        a_frag[kk] = *reinterpret_cast<const short8*>(
            &xs[(wave * 16 + lr) * 256 + kk * 32 + lh * 8]);

    wstore();
    __syncthreads();
    wload(1);

    for (int j = 0; j < 12; ++j) {
        const int z = j >> 2, cc = j & 3;

        f32x4 acc[4];
        #pragma unroll
        for (int cb = 0; cb < 4; ++cb) acc[cb] = (f32x4)(0.0f);

        __builtin_amdgcn_s_setprio(1);
        #pragma unroll
        for (int kk = 0; kk < 8; ++kk) {
            #pragma unroll
            for (int cb = 0; cb < 4; ++cb) {
                short8 b_frag = *reinterpret_cast<const short8*>(
                    wchunk + (cb * 16 + lr) * 512 + (((kk * 4 + lh) ^ (lr & 7)) * 16));
                acc[cb] = mfma32(a_frag[kk], b_frag, acc[cb]);
            }
        }
        __builtin_amdgcn_s_setprio(0);

        if (z < 2) {
            const float* bias = (z == 0) ? bq : bk;
            const float bs = (z == 0) ? 0.0625f : 1.0f;
            #pragma unroll
            for (int cb = 0; cb < 4; ++cb) {
                int c = cc * 64 + cb * 16 + lr;
                float bb_ = bias[c] * bs;
                #pragma unroll
                for (int r = 0; r < 4; ++r)
                    xs[(wave * 16 + lh * 4 + r) * 256 + c] = f2bf(acc[cb][r] + bb_);
            }
        } else {
            char* xc = (char*)xs;
            #pragma unroll
            for (int cb = 0; cb < 4; ++cb) {
                int c = cc * 64 + cb * 16 + lr;
                float bb_ = bv[c];
                #pragma unroll
                for (int r = 0; r < 4; ++r) {
                    int n = wave * 16 + lh * 4 + r;
                    *reinterpret_cast<unsigned short*>(
                        xc + c * 128 + (((n >> 3) ^ (c & 7)) * 16) + (n & 7) * 2)
                        = f2bf(acc[cb][r] + bb_);
                }
            }
        }
        __syncthreads();

        if (cc == 3) {
            if (z == 0) {
                char* dst = (char*)q_ws + m0 * 512;
                const char* src = (const char*)xs;
                #pragma unroll
                for (int i = 0; i < 8; ++i) {
                    int g = i * 4096 + t * 16;
                    *reinterpret_cast<short8*>(dst + g) =
                        *reinterpret_cast<const short8*>(src + g);
                }
            } else if (z == 1) {
                char* dst = (char*)k_img + img_base;
                #pragma unroll
                for (int i = 0; i < 8; ++i) {
                    int g = i * 4096 + t * 16;
                    int row = g >> 9, sp = (g >> 4) & 31;
                    int s = sp ^ (row & 7);
                    *reinterpret_cast<short8*>(dst + g) =
                        *reinterpret_cast<const short8*>(&xs[row * 256 + s * 8]);
                }
            } else {
                char* dst = (char*)v_img + img_base;
                const char* src = (const char*)xs;
                #pragma unroll
                for (int i = 0; i < 8; ++i) {
                    int g = i * 4096 + t * 16;
                    *reinterpret_cast<short8*>(dst + g) =
                        *reinterpret_cast<const short8*>(src + g);
                }
            }
        }

        if (j < 11) wstore();
        if (j < 10) wload(j + 2);
        __syncthreads();
    }
}

// ---------- kernel 3: fused flash attention (32x32 MFMA) + projection + residual ----------
// 256 blocks, 8 waves x 32 q rows. Swapped QK^T via mfma_32x32x16 (lane owns one
// q column), in-register softmax (T12: cvt_pk + shfl_xor(32) P redistribution),
// full-rate 32x32 PV, global_load_lds double-buffered K/V staging.
__global__ __launch_bounds__(512, 2) void attn_kernel(
    const unsigned short* __restrict__ q_ws,
    const unsigned short* __restrict__ k_img,
    const unsigned short* __restrict__ v_img,
    const unsigned short* __restrict__ wpt,
    const float* __restrict__ bp,
    const float* __restrict__ x,
    float* __restrict__ out)
{
    extern __shared__ char smem[];
    char* ksb = smem;             // 2 x 32KB K tiles [64 k][512B], slot ^= row&7
    char* vsb = smem + 65536;     // 2 x 32KB V tiles [256 c][128B], slot ^= c&7
    const int t = threadIdx.x;
    const int wave = t >> 6, lane = t & 63;
    const int q32 = lane & 31;    // lane's q column (and K/V row index)
    const int u   = lane >> 5;
    const int lr = lane & 15, lh = lane >> 4;   // for 16x16 proj epilogue

    // XCD-aware mapping: batch b's 16 blocks all live on XCD b>>1
    const int bid = blockIdx.x;
    const int xcd = bid & 7, ii = bid >> 3;
    const int b = (xcd << 1) | (ii & 1);
    const int qc = ii >> 1;
    const long qbase = (long)b * NTOK + qc * 256 + wave * 32;

    const char* kg = (const char*)k_img + ((long)b * 64) * 32768;
    const char* vg = (const char*)v_img + ((long)b * 64) * 32768;

    // resident Q (B-operand): qf[kk] = Q[qbase+q32][kk*16 + u*8 .. +8], scale folded
    short8 qf[16];
    #pragma unroll
    for (int kk = 0; kk < 16; ++kk)
        qf[kk] = *reinterpret_cast<const short8*>(
            &q_ws[(qbase + q32) * 256 + kk * 16 + u * 8]);

    // acc[cb]: O^T[c = cb*32 + (r&3)+8*(r>>2)+4u][q32]
    f32x16 acc[8];
    #pragma unroll
    for (int cb = 0; cb < 8; ++cb) acc[cb] = (f32x16)(0.0f);
    float m_run = -INFINITY, l_run = 0.f;

    auto stage = [&](int nb, int tt) {
        const char* ks = kg + (long)tt * 32768 + wave * 4096 + lane * 16;
        char* kd = ksb + nb * 32768 + wave * 4096;
        #pragma unroll
        for (int i = 0; i < 4; ++i) ldsdma16(kd + i * 1024, ks + i * 1024);
        const char* vs = vg + (long)tt * 32768 + wave * 4096 + lane * 16;
        char* vd = vsb + nb * 32768 + wave * 4096;
        #pragma unroll
        for (int i = 0; i < 4; ++i) ldsdma16(vd + i * 1024, vs + i * 1024);
    };

    stage(0, 0);
    __syncthreads();

    for (int tt = 0; tt < 64; ++tt) {
        const int buf = tt & 1;
        if (tt < 63) stage(buf ^ 1, tt + 1);   // issue early; barrier drains it
        const char* kb = ksb + buf * 32768;
        const char* vb = vsb + buf * 32768;

        #pragma unroll
        for (int h = 0; h < 2; ++h) {
            // ---- QK^T: S^T[32 k][32 q] in one f32x16 ----
            f32x16 s = (f32x16)(0.0f);
            __builtin_amdgcn_s_setprio(1);
            #pragma unroll
            for (int kk = 0; kk < 16; ++kk) {
                short8 kf = *reinterpret_cast<const short8*>(
                    kb + (h * 32 + q32) * 512 + (((kk * 2 + u) ^ (q32 & 7)) * 16));
                s = mfma32x32(kf, qf[kk], s);
            }
            __builtin_amdgcn_s_setprio(0);

            // ---- in-register online softmax (lane owns q; 16 k vals + partner) ----
            float mt = fmaxf(fmaxf(fmaxf(s[0], s[1]), fmaxf(s[2], s[3])),
                             fmaxf(fmaxf(s[4], s[5]), fmaxf(s[6], s[7])));
            mt = fmaxf(mt, fmaxf(fmaxf(fmaxf(s[8], s[9]), fmaxf(s[10], s[11])),
                                 fmaxf(fmaxf(s[12], s[13]), fmaxf(s[14], s[15]))));
            mt = fmaxf(mt, __shfl_xor(mt, 32));
            if (!__all(mt <= m_run + 8.0f)) {     // defer-max (T13)
                float mn = fmaxf(m_run, mt);
                float a = __expf(m_run - mn);
                l_run *= a;
                #pragma unroll
                for (int cb = 0; cb < 8; ++cb)
                    #pragma unroll
                    for (int r = 0; r < 16; ++r) acc[cb][r] *= a;
                m_run = mn;
            }
            unsigned plo[4], phi[4];
            float rs = 0.f;
            #pragma unroll
            for (int m = 0; m < 4; ++m) {
                float e0 = __expf(s[4*m+0] - m_run);
                float e1 = __expf(s[4*m+1] - m_run);
                float e2 = __expf(s[4*m+2] - m_run);
                float e3 = __expf(s[4*m+3] - m_run);
                rs += (e0 + e1) + (e2 + e3);
                plo[m] = cvt_pk_bf16(e0, e1);   // k = 8m+4u+0,1
                phi[m] = cvt_pk_bf16(e2, e3);   // k = 8m+4u+2,3
            }
            rs += __shfl_xor(rs, 32);
            l_run += rs;

            // ---- PV: acc[c][q] += V^T[c][k16] @ P^T[k16][q], two K=16 steps ----
            #pragma unroll
            for (int tp = 0; tp < 2; ++tp) {
                // B-frag k = 16*tp + 8u + j. Lane (q,u) needs P_lo/P_hi[2tp+u]
                // from BOTH 32-lane halves (own + partner via shfl_xor 32).
                unsigned xl = plo[2*tp], yl = plo[2*tp+1];
                unsigned xh = phi[2*tp], yh = phi[2*tp+1];
                unsigned xls = __shfl_xor(xl, 32);
                unsigned yls = __shfl_xor(yl, 32);
                unsigned xhs = __shfl_xor(xh, 32);
                unsigned yhs = __shfl_xor(yh, 32);
                union { unsigned w[4]; short8 v; } pf;
                pf.w[0] = u ? yls : xl;    // k pair (16tp+8u+0,1)  from u_s=0
                pf.w[1] = u ? yhs : xh;    // k pair (+2,+3)        from u_s=0
                pf.w[2] = u ? yl  : xls;   // k pair (+4,+5)        from u_s=1
                pf.w[3] = u ? yh  : xhs;   // k pair (+6,+7)        from u_s=1
                __builtin_amdgcn_s_setprio(1);
                #pragma unroll
                for (int cb = 0; cb < 8; ++cb) {
                    int c = cb * 32 + q32;
                    short8 vf = *reinterpret_cast<const short8*>(
                        vb + c * 128 + (((h * 4 + 2 * tp + u) ^ (c & 7)) * 16));
                    acc[cb] = mfma32x32(vf, pf.v, acc[cb]);
                }
                __builtin_amdgcn_s_setprio(0);
            }
        }
        __syncthreads();   // drains DMA for tile tt+1; K/V readers done
    }

    // ---- epilogue: O^T -> per-wave LDS transpose (swizzled, paired b32 writes) ----
    __syncthreads();   // all waves done with ksb/vsb before overwriting with ot
    float inv = 1.0f / l_run;
    char* ot = smem + wave * 16384;   // [32 q][512B], slot ^= q&7
    #pragma unroll
    for (int cb = 0; cb < 8; ++cb) {
        #pragma unroll
        for (int i = 0; i < 8; ++i) {
            int c = cb * 32 + ((2 * i) & 3) + 8 * (i >> 1) + 4 * u;
            unsigned w = cvt_pk_bf16(acc[cb][2*i] * inv, acc[cb][2*i+1] * inv);
            *reinterpret_cast<unsigned*>(
                ot + q32 * 512 + (((c >> 3) ^ (q32 & 7)) * 16) + (c & 7) * 2) = w;
        }
    }

    // ---- fused projection: OUT = O @ Wp + bp + x (16x16x32, per-wave ot) ----
    f32x4 po[2][16];
    #pragma unroll
    for (int qb = 0; qb < 2; ++qb)
        #pragma unroll
        for (int cb = 0; cb < 16; ++cb) po[qb][cb] = (f32x4)(0.0f);

    for (int kk = 0; kk < 8; ++kk) {
        int slot = (kk * 4 + lh);
        short8 a0 = *reinterpret_cast<const short8*>(
            ot + (0 * 16 + lr) * 512 + ((slot ^ (lr & 7)) * 16));
        short8 a1 = *reinterpret_cast<const short8*>(
            ot + (1 * 16 + lr) * 512 + ((slot ^ (lr & 7)) * 16));
        #pragma unroll
        for (int cb = 0; cb < 16; ++cb) {
            short8 bf_ = *reinterpret_cast<const short8*>(
                &wpt[(cb * 16 + lr) * 256 + kk * 32 + lh * 8]);
            po[0][cb] = mfma32(a0, bf_, po[0][cb]);
            po[1][cb] = mfma32(a1, bf_, po[1][cb]);
        }
    }

    #pragma unroll
    for (int qb = 0; qb < 2; ++qb) {
        #pragma unroll
        for (int cb = 0; cb < 16; ++cb) {
            int c = cb * 16 + lr;
            float bias = bp[c];
            #pragma unroll
            for (int r = 0; r < 4; ++r) {
                long row = qbase + qb * 16 + lh * 4 + r;
                out[row * 256 + c] = po[qb][cb][r] + bias + x[row * 256 + c];
            }
        }
    }
}

extern "C" void kernel_launch(void* const* d_in, const int* in_sizes, int n_in,
                              void* d_out, int out_size, void* d_ws, size_t ws_size,
                              hipStream_t stream) {
    const float* x  = (const float*)d_in[0];
    const float* wq = (const float*)d_in[1];
    const float* bq = (const float*)d_in[2];
    const float* wk = (const float*)d_in[3];
    const float* bk = (const float*)d_in[4];
    const float* wv = (const float*)d_in[5];
    const float* bv = (const float*)d_in[6];
    const float* wp = (const float*)d_in[7];
    const float* bp = (const float*)d_in[8];
    float* out = (float*)d_out;

    char* ws = (char*)d_ws;
    unsigned short* wt_all = (unsigned short*)ws;               // 512 KiB
    unsigned short* q_ws   = (unsigned short*)(ws + 524288);    // 32 MiB
    unsigned short* k_img  = q_ws + (size_t)MROWS * CDIM;       // 32 MiB
    unsigned short* v_img  = k_img + (size_t)MROWS * CDIM;      // 32 MiB

    prep_w_kernel<<<dim3(256, 4), 256, 0, stream>>>(wq, wk, wv, wp, wt_all);
    qkv_kernel<<<dim3(MROWS / 64), 256, 0, stream>>>(x, wt_all, bq, bk, bv,
                                                     q_ws, k_img, v_img);
    hipFuncSetAttribute((const void*)attn_kernel,
                        hipFuncAttributeMaxDynamicSharedMemorySize, 131072);
    attn_kernel<<<dim3(256), 512, 131072, stream>>>(q_ws, k_img, v_img,
                                                    wt_all + 3 * 65536, bp, x, out);
}

// Round 8
// 372.493 us; speedup vs baseline: 1.0125x; 1.0072x over previous
//
#include <hip/hip_runtime.h>
#include <hip/hip_bf16.h>
#include <math.h>

// ---------- types ----------
typedef __attribute__((ext_vector_type(8))) short short8;    // 8 x bf16
typedef __attribute__((ext_vector_type(4))) float f32x4;
typedef __attribute__((ext_vector_type(16))) float f32x16;

// B=16, H=W=64 -> N=4096 tokens/batch, C=256, M = B*N = 65536
#define NTOK 4096
#define CDIM 256
#define MROWS 65536

static __device__ __forceinline__ unsigned short f2bf(float f) {
    union { float f; unsigned int u; } v; v.f = f;
    unsigned int u = v.u;
    return (unsigned short)((u + 0x7fffu + ((u >> 16) & 1u)) >> 16);  // RNE
}

static __device__ __forceinline__ unsigned cvt_pk_bf16(float lo, float hi) {
    unsigned r;
    asm("v_cvt_pk_bf16_f32 %0, %1, %2" : "=v"(r) : "v"(lo), "v"(hi));
    return r;
}

static __device__ __forceinline__ f32x4 mfma32(short8 a, short8 b, f32x4 c) {
    return __builtin_amdgcn_mfma_f32_16x16x32_bf16(a, b, c, 0, 0, 0);
}

static __device__ __forceinline__ f32x16 mfma32x32(short8 a, short8 b, f32x16 c) {
    return __builtin_amdgcn_mfma_f32_32x32x16_bf16(a, b, c, 0, 0, 0);
}

// async global -> LDS DMA, 16B per lane (dst = wave-uniform base + lane*16)
static __device__ __forceinline__ void ldsdma16(char* l, const char* g) {
    __builtin_amdgcn_global_load_lds(
        (const __attribute__((address_space(1))) unsigned int*)g,
        (__attribute__((address_space(3))) unsigned int*)l,
        16, 0, 0);
}

// ---------- kernel 1: transpose + convert weights to bf16 ----------
// wt_all[z][c_out][c_in] = w_z[c_in][c_out]; z=0 (Wq) folds in the 1/16 scale.
__global__ __launch_bounds__(256) void prep_w_kernel(
    const float* __restrict__ wq, const float* __restrict__ wk,
    const float* __restrict__ wv, const float* __restrict__ wp,
    unsigned short* __restrict__ wt_all)
{
    const int o = blockIdx.x;      // c_out
    const int t = threadIdx.x;     // c_in
    const int z = blockIdx.y;
    const float* w = (z == 0) ? wq : (z == 1) ? wk : (z == 2) ? wv : wp;
    const float s = (z == 0) ? 0.0625f : 1.0f;
    wt_all[z * 65536 + o * 256 + t] = f2bf(w[t * 256 + o] * s);
}

// ---------- kernel 2: QKV projections (weights streamed through LDS) ----------
__global__ __launch_bounds__(256) void qkv_kernel(
    const float* __restrict__ x,
    const unsigned short* __restrict__ wt_all,
    const float* __restrict__ bq, const float* __restrict__ bk,
    const float* __restrict__ bv,
    unsigned short* __restrict__ q_ws, unsigned short* __restrict__ k_img,
    unsigned short* __restrict__ v_img)
{
    __shared__ unsigned short xs[64 * 256];   // 32 KB: X tile, then result staging
    __shared__ char wchunk[32768];            // 64 c_out x 512B (swizzled 16B slots)
    const int t = threadIdx.x;
    const long m0 = (long)blockIdx.x * 64;
    const int bb = (int)(m0 >> 12);
    const int tile = (int)((m0 & 4095) >> 6);
    const long img_base = ((long)bb * 64 + tile) * 32768;  // bytes

    const int wave = t >> 6, lane = t & 63;
    const int lr = lane & 15, lh = lane >> 4;

    // weight chunk staging: global -> regs -> swizzled LDS
    short8 wreg[8];
    auto wload = [&](int j) {   // chunk j in 0..11 (z = j>>2, cc = j&3)
        const char* src = (const char*)wt_all + (long)j * 32768 + t * 16;
        #pragma unroll
        for (int i = 0; i < 8; ++i)
            wreg[i] = *reinterpret_cast<const short8*>(src + i * 4096);
    };
    auto wstore = [&]() {
        #pragma unroll
        for (int i = 0; i < 8; ++i) {
            int g = i * 4096 + t * 16;
            int row = g >> 9, slot = (g >> 4) & 31;
            *reinterpret_cast<short8*>(
                wchunk + row * 512 + ((slot ^ (row & 7)) * 16)) = wreg[i];
        }
    };

    wload(0);

    // stage X tile (fp32 -> bf16) into LDS
    #pragma unroll
    for (int i = 0; i < 16; ++i) {
        int idx = i * 256 + t;
        int row = idx >> 6;
        int c4 = (idx & 63) << 2;
        float4 v = *reinterpret_cast<const float4*>(x + (m0 + row) * CDIM + c4);
        ushort4 pk;
        pk.x = f2bf(v.x); pk.y = f2bf(v.y); pk.z = f2bf(v.z); pk.w = f2bf(v.w);
        *reinterpret_cast<ushort4*>(&xs[row * 256 + c4]) = pk;
    }
    __syncthreads();

    short8 a_frag[8];
    #pragma unroll
    for (int kk = 0; kk < 8; ++kk)
        a_frag[kk] = *reinterpret_cast<const short8*>(
            &xs[(wave * 16 + lr) * 256 + kk * 32 + lh * 8]);

    wstore();
    __syncthreads();
    wload(1);

    for (int j = 0; j < 12; ++j) {
        const int z = j >> 2, cc = j & 3;

        f32x4 acc[4];
        #pragma unroll
        for (int cb = 0; cb < 4; ++cb) acc[cb] = (f32x4)(0.0f);

        __builtin_amdgcn_s_setprio(1);
        #pragma unroll
        for (int kk = 0; kk < 8; ++kk) {
            #pragma unroll
            for (int cb = 0; cb < 4; ++cb) {
                short8 b_frag = *reinterpret_cast<const short8*>(
                    wchunk + (cb * 16 + lr) * 512 + (((kk * 4 + lh) ^ (lr & 7)) * 16));
                acc[cb] = mfma32(a_frag[kk], b_frag, acc[cb]);
            }
        }
        __builtin_amdgcn_s_setprio(0);

        if (z < 2) {
            const float* bias = (z == 0) ? bq : bk;
            const float bs = (z == 0) ? 0.0625f : 1.0f;
            #pragma unroll
            for (int cb = 0; cb < 4; ++cb) {
                int c = cc * 64 + cb * 16 + lr;
                float bb_ = bias[c] * bs;
                #pragma unroll
                for (int r = 0; r < 4; ++r)
                    xs[(wave * 16 + lh * 4 + r) * 256 + c] = f2bf(acc[cb][r] + bb_);
            }
        } else {
            char* xc = (char*)xs;
            #pragma unroll
            for (int cb = 0; cb < 4; ++cb) {
                int c = cc * 64 + cb * 16 + lr;
                float bb_ = bv[c];
                #pragma unroll
                for (int r = 0; r < 4; ++r) {
                    int n = wave * 16 + lh * 4 + r;
                    *reinterpret_cast<unsigned short*>(
                        xc + c * 128 + (((n >> 3) ^ (c & 7)) * 16) + (n & 7) * 2)
                        = f2bf(acc[cb][r] + bb_);
                }
            }
        }
        __syncthreads();

        if (cc == 3) {
            if (z == 0) {
                char* dst = (char*)q_ws + m0 * 512;
                const char* src = (const char*)xs;
                #pragma unroll
                for (int i = 0; i < 8; ++i) {
                    int g = i * 4096 + t * 16;
                    *reinterpret_cast<short8*>(dst + g) =
                        *reinterpret_cast<const short8*>(src + g);
                }
            } else if (z == 1) {
                char* dst = (char*)k_img + img_base;
                #pragma unroll
                for (int i = 0; i < 8; ++i) {
                    int g = i * 4096 + t * 16;
                    int row = g >> 9, sp = (g >> 4) & 31;
                    int s = sp ^ (row & 7);
                    *reinterpret_cast<short8*>(dst + g) =
                        *reinterpret_cast<const short8*>(&xs[row * 256 + s * 8]);
                }
            } else {
                char* dst = (char*)v_img + img_base;
                const char* src = (const char*)xs;
                #pragma unroll
                for (int i = 0; i < 8; ++i) {
                    int g = i * 4096 + t * 16;
                    *reinterpret_cast<short8*>(dst + g) =
                        *reinterpret_cast<const short8*>(src + g);
                }
            }
        }

        if (j < 11) wstore();
        if (j < 10) wload(j + 2);
        __syncthreads();
    }
}

// ---------- kernel 3: fused flash attention (32x32 MFMA) + projection + residual ----------
// 256 blocks, 8 waves x 32 q rows. Swapped QK^T via mfma_32x32x16 (lane owns one
// q column), in-register softmax (T12: cvt_pk + shfl_xor(32) P redistribution),
// full-rate 32x32 PV, global_load_lds double-buffered K/V staging.
__global__ __launch_bounds__(512, 2) void attn_kernel(
    const unsigned short* __restrict__ q_ws,
    const unsigned short* __restrict__ k_img,
    const unsigned short* __restrict__ v_img,
    const unsigned short* __restrict__ wpt,
    const float* __restrict__ bp,
    const float* __restrict__ x,
    float* __restrict__ out)
{
    extern __shared__ char smem[];
    char* ksb = smem;             // 2 x 32KB K tiles [64 k][512B], slot ^= row&7
    char* vsb = smem + 65536;     // 2 x 32KB V tiles [256 c][128B], slot ^= c&7
    const int t = threadIdx.x;
    const int wave = t >> 6, lane = t & 63;
    const int q32 = lane & 31;    // lane's q column (and K/V row index)
    const int u   = lane >> 5;
    const int lr = lane & 15, lh = lane >> 4;   // for 16x16 proj epilogue

    // XCD-aware mapping: batch b's 16 blocks all live on XCD b>>1
    const int bid = blockIdx.x;
    const int xcd = bid & 7, ii = bid >> 3;
    const int b = (xcd << 1) | (ii & 1);
    const int qc = ii >> 1;
    const long qbase = (long)b * NTOK + qc * 256 + wave * 32;

    const char* kg = (const char*)k_img + ((long)b * 64) * 32768;
    const char* vg = (const char*)v_img + ((long)b * 64) * 32768;

    // resident Q (B-operand): qf[kk] = Q[qbase+q32][kk*16 + u*8 .. +8], scale folded
    short8 qf[16];
    #pragma unroll
    for (int kk = 0; kk < 16; ++kk)
        qf[kk] = *reinterpret_cast<const short8*>(
            &q_ws[(qbase + q32) * 256 + kk * 16 + u * 8]);

    // acc[cb]: O^T[c = cb*32 + (r&3)+8*(r>>2)+4u][q32]
    f32x16 acc[8];
    #pragma unroll
    for (int cb = 0; cb < 8; ++cb) acc[cb] = (f32x16)(0.0f);
    float m_run = -INFINITY, l_run = 0.f;

    auto stage = [&](int nb, int tt) {
        const char* ks = kg + (long)tt * 32768 + wave * 4096 + lane * 16;
        char* kd = ksb + nb * 32768 + wave * 4096;
        #pragma unroll
        for (int i = 0; i < 4; ++i) ldsdma16(kd + i * 1024, ks + i * 1024);
        const char* vs = vg + (long)tt * 32768 + wave * 4096 + lane * 16;
        char* vd = vsb + nb * 32768 + wave * 4096;
        #pragma unroll
        for (int i = 0; i < 4; ++i) ldsdma16(vd + i * 1024, vs + i * 1024);
    };

    stage(0, 0);
    __syncthreads();

    for (int tt = 0; tt < 64; ++tt) {
        const int buf = tt & 1;
        if (tt < 63) stage(buf ^ 1, tt + 1);   // issue early; barrier drains it
        const char* kb = ksb + buf * 32768;
        const char* vb = vsb + buf * 32768;

        #pragma unroll
        for (int h = 0; h < 2; ++h) {
            // ---- QK^T: S^T[32 k][32 q] in one f32x16 ----
            f32x16 s = (f32x16)(0.0f);
            __builtin_amdgcn_s_setprio(1);
            #pragma unroll
            for (int kk = 0; kk < 16; ++kk) {
                short8 kf = *reinterpret_cast<const short8*>(
                    kb + (h * 32 + q32) * 512 + (((kk * 2 + u) ^ (q32 & 7)) * 16));
                s = mfma32x32(kf, qf[kk], s);
            }
            __builtin_amdgcn_s_setprio(0);

            // ---- in-register online softmax (lane owns q; 16 k vals + partner) ----
            float mt = fmaxf(fmaxf(fmaxf(s[0], s[1]), fmaxf(s[2], s[3])),
                             fmaxf(fmaxf(s[4], s[5]), fmaxf(s[6], s[7])));
            mt = fmaxf(mt, fmaxf(fmaxf(fmaxf(s[8], s[9]), fmaxf(s[10], s[11])),
                                 fmaxf(fmaxf(s[12], s[13]), fmaxf(s[14], s[15]))));
            mt = fmaxf(mt, __shfl_xor(mt, 32));
            if (!__all(mt <= m_run + 8.0f)) {     // defer-max (T13)
                float mn = fmaxf(m_run, mt);
                float a = __expf(m_run - mn);
                l_run *= a;
                #pragma unroll
                for (int cb = 0; cb < 8; ++cb)
                    #pragma unroll
                    for (int r = 0; r < 16; ++r) acc[cb][r] *= a;
                m_run = mn;
            }
            unsigned plo[4], phi[4];
            float rs = 0.f;
            #pragma unroll
            for (int m = 0; m < 4; ++m) {
                float e0 = __expf(s[4*m+0] - m_run);
                float e1 = __expf(s[4*m+1] - m_run);
                float e2 = __expf(s[4*m+2] - m_run);
                float e3 = __expf(s[4*m+3] - m_run);
                rs += (e0 + e1) + (e2 + e3);
                plo[m] = cvt_pk_bf16(e0, e1);   // k = 8m+4u+0,1
                phi[m] = cvt_pk_bf16(e2, e3);   // k = 8m+4u+2,3
            }
            rs += __shfl_xor(rs, 32);
            l_run += rs;

            // ---- PV: acc[c][q] += V^T[c][k16] @ P^T[k16][q], two K=16 steps ----
            #pragma unroll
            for (int tp = 0; tp < 2; ++tp) {
                // B-frag k = 16*tp + 8u + j. Lane (q,u) needs P_lo/P_hi[2tp+u]
                // from BOTH 32-lane halves (own + partner via shfl_xor 32).
                unsigned xl = plo[2*tp], yl = plo[2*tp+1];
                unsigned xh = phi[2*tp], yh = phi[2*tp+1];
                unsigned xls = __shfl_xor(xl, 32);
                unsigned yls = __shfl_xor(yl, 32);
                unsigned xhs = __shfl_xor(xh, 32);
                unsigned yhs = __shfl_xor(yh, 32);
                union { unsigned w[4]; short8 v; } pf;
                pf.w[0] = u ? yls : xl;    // k pair (16tp+8u+0,1)  from u_s=0
                pf.w[1] = u ? yhs : xh;    // k pair (+2,+3)        from u_s=0
                pf.w[2] = u ? yl  : xls;   // k pair (+4,+5)        from u_s=1
                pf.w[3] = u ? yh  : xhs;   // k pair (+6,+7)        from u_s=1
                __builtin_amdgcn_s_setprio(1);
                #pragma unroll
                for (int cb = 0; cb < 8; ++cb) {
                    int c = cb * 32 + q32;
                    short8 vf = *reinterpret_cast<const short8*>(
                        vb + c * 128 + (((h * 4 + 2 * tp + u) ^ (c & 7)) * 16));
                    acc[cb] = mfma32x32(vf, pf.v, acc[cb]);
                }
                __builtin_amdgcn_s_setprio(0);
            }
        }
        __syncthreads();   // drains DMA for tile tt+1; K/V readers done
    }

    // ---- epilogue: O^T -> per-wave LDS transpose (swizzled, paired b32 writes) ----
    __syncthreads();   // all waves done with ksb/vsb before overwriting with ot
    float inv = 1.0f / l_run;
    char* ot = smem + wave * 16384;   // [32 q][512B], slot ^= q&7
    #pragma unroll
    for (int cb = 0; cb < 8; ++cb) {
        #pragma unroll
        for (int i = 0; i < 8; ++i) {
            int c = cb * 32 + ((2 * i) & 3) + 8 * (i >> 1) + 4 * u;
            unsigned w = cvt_pk_bf16(acc[cb][2*i] * inv, acc[cb][2*i+1] * inv);
            *reinterpret_cast<unsigned*>(
                ot + q32 * 512 + (((c >> 3) ^ (q32 & 7)) * 16) + (c & 7) * 2) = w;
        }
    }

    // ---- fused projection: OUT = O @ Wp + bp + x (16x16x32, per-wave ot) ----
    f32x4 po[2][16];
    #pragma unroll
    for (int qb = 0; qb < 2; ++qb)
        #pragma unroll
        for (int cb = 0; cb < 16; ++cb) po[qb][cb] = (f32x4)(0.0f);

    for (int kk = 0; kk < 8; ++kk) {
        int slot = (kk * 4 + lh);
        short8 a0 = *reinterpret_cast<const short8*>(
            ot + (0 * 16 + lr) * 512 + ((slot ^ (lr & 7)) * 16));
        short8 a1 = *reinterpret_cast<const short8*>(
            ot + (1 * 16 + lr) * 512 + ((slot ^ (lr & 7)) * 16));
        #pragma unroll
        for (int cb = 0; cb < 16; ++cb) {
            short8 bf_ = *reinterpret_cast<const short8*>(
                &wpt[(cb * 16 + lr) * 256 + kk * 32 + lh * 8]);
            po[0][cb] = mfma32(a0, bf_, po[0][cb]);
            po[1][cb] = mfma32(a1, bf_, po[1][cb]);
        }
    }

    #pragma unroll
    for (int qb = 0; qb < 2; ++qb) {
        #pragma unroll
        for (int cb = 0; cb < 16; ++cb) {
            int c = cb * 16 + lr;
            float bias = bp[c];
            #pragma unroll
            for (int r = 0; r < 4; ++r) {
                long row = qbase + qb * 16 + lh * 4 + r;
                out[row * 256 + c] = po[qb][cb][r] + bias + x[row * 256 + c];
            }
        }
    }
}

extern "C" void kernel_launch(void* const* d_in, const int* in_sizes, int n_in,
                              void* d_out, int out_size, void* d_ws, size_t ws_size,
                              hipStream_t stream) {
    const float* x  = (const float*)d_in[0];
    const float* wq = (const float*)d_in[1];
    const float* bq = (const float*)d_in[2];
    const float* wk = (const float*)d_in[3];
    const float* bk = (const float*)d_in[4];
    const float* wv = (const float*)d_in[5];
    const float* bv = (const float*)d_in[6];
    const float* wp = (const float*)d_in[7];
    const float* bp = (const float*)d_in[8];
    float* out = (float*)d_out;

    char* ws = (char*)d_ws;
    unsigned short* wt_all = (unsigned short*)ws;               // 512 KiB
    unsigned short* q_ws   = (unsigned short*)(ws + 524288);    // 32 MiB
    unsigned short* k_img  = q_ws + (size_t)MROWS * CDIM;       // 32 MiB
    unsigned short* v_img  = k_img + (size_t)MROWS * CDIM;      // 32 MiB

    prep_w_kernel<<<dim3(256, 4), 256, 0, stream>>>(wq, wk, wv, wp, wt_all);
    qkv_kernel<<<dim3(MROWS / 64), 256, 0, stream>>>(x, wt_all, bq, bk, bv,
                                                     q_ws, k_img, v_img);
    hipFuncSetAttribute((const void*)attn_kernel,
                        hipFuncAttributeMaxDynamicSharedMemorySize, 131072);
    attn_kernel<<<dim3(256), 512, 131072, stream>>>(q_ws, k_img, v_img,
                                                    wt_all + 3 * 65536, bp, x, out);
}

// Round 9
// 366.621 us; speedup vs baseline: 1.0287x; 1.0160x over previous
//
#include <hip/hip_runtime.h>
#include <hip/hip_bf16.h>
#include <math.h>

// ---------- types ----------
typedef __attribute__((ext_vector_type(8))) short short8;    // 8 x bf16
typedef __attribute__((ext_vector_type(4))) float f32x4;
typedef __attribute__((ext_vector_type(16))) float f32x16;

// B=16, H=W=64 -> N=4096 tokens/batch, C=256, M = B*N = 65536
#define NTOK 4096
#define CDIM 256
#define MROWS 65536
#define LOG2E 1.44269504088896f

static __device__ __forceinline__ unsigned short f2bf(float f) {
    union { float f; unsigned int u; } v; v.f = f;
    unsigned int u = v.u;
    return (unsigned short)((u + 0x7fffu + ((u >> 16) & 1u)) >> 16);  // RNE
}

static __device__ __forceinline__ unsigned cvt_pk_bf16(float lo, float hi) {
    unsigned r;
    asm("v_cvt_pk_bf16_f32 %0, %1, %2" : "=v"(r) : "v"(lo), "v"(hi));
    return r;
}

static __device__ __forceinline__ float fexp2(float x) {
#if __has_builtin(__builtin_amdgcn_exp2f)
    return __builtin_amdgcn_exp2f(x);
#else
    return exp2f(x);
#endif
}

// v_permlane32_swap_b32: after the op, a = {a.lo, b.lo}, b = {a.hi, b.hi}
// (VALU cross-lane — does NOT touch the LDS pipe, unlike __shfl/ds_bpermute)
static __device__ __forceinline__ void permlane32_swap(unsigned& a, unsigned& b) {
#if __has_builtin(__builtin_amdgcn_permlane32_swap)
    auto r = __builtin_amdgcn_permlane32_swap(a, b, false, false);
    a = r[0]; b = r[1];
#else
    asm volatile("v_permlane32_swap_b32 %0, %1" : "+v"(a), "+v"(b));
#endif
}

static __device__ __forceinline__ float xor32_max(float x) {
    unsigned a = __float_as_uint(x), b = a;
    permlane32_swap(a, b);
    return fmaxf(__uint_as_float(a), __uint_as_float(b));
}

static __device__ __forceinline__ float xor32_sum(float x) {
    unsigned a = __float_as_uint(x), b = a;
    permlane32_swap(a, b);
    return __uint_as_float(a) + __uint_as_float(b);
}

static __device__ __forceinline__ f32x4 mfma32(short8 a, short8 b, f32x4 c) {
    return __builtin_amdgcn_mfma_f32_16x16x32_bf16(a, b, c, 0, 0, 0);
}

static __device__ __forceinline__ f32x16 mfma32x32(short8 a, short8 b, f32x16 c) {
    return __builtin_amdgcn_mfma_f32_32x32x16_bf16(a, b, c, 0, 0, 0);
}

// async global -> LDS DMA, 16B per lane (dst = wave-uniform base + lane*16)
static __device__ __forceinline__ void ldsdma16(char* l, const char* g) {
    __builtin_amdgcn_global_load_lds(
        (const __attribute__((address_space(1))) unsigned int*)g,
        (__attribute__((address_space(3))) unsigned int*)l,
        16, 0, 0);
}

// ---------- kernel 1: transpose + convert weights to bf16 ----------
// wt_all[z][c_out][c_in] = w_z[c_in][c_out]; z=0 (Wq) folds in 1/16 AND log2(e)
// (softmax runs in the exp2 domain).
__global__ __launch_bounds__(256) void prep_w_kernel(
    const float* __restrict__ wq, const float* __restrict__ wk,
    const float* __restrict__ wv, const float* __restrict__ wp,
    unsigned short* __restrict__ wt_all)
{
    const int o = blockIdx.x;      // c_out
    const int t = threadIdx.x;     // c_in
    const int z = blockIdx.y;
    const float* w = (z == 0) ? wq : (z == 1) ? wk : (z == 2) ? wv : wp;
    const float s = (z == 0) ? 0.0625f * LOG2E : 1.0f;
    wt_all[z * 65536 + o * 256 + t] = f2bf(w[t * 256 + o] * s);
}

// ---------- kernel 2: QKV projections (weights streamed through LDS) ----------
__global__ __launch_bounds__(256) void qkv_kernel(
    const float* __restrict__ x,
    const unsigned short* __restrict__ wt_all,
    const float* __restrict__ bq, const float* __restrict__ bk,
    const float* __restrict__ bv,
    unsigned short* __restrict__ q_ws, unsigned short* __restrict__ k_img,
    unsigned short* __restrict__ v_img)
{
    __shared__ unsigned short xs[64 * 256];   // 32 KB: X tile, then result staging
    __shared__ char wchunk[32768];            // 64 c_out x 512B (swizzled 16B slots)
    const int t = threadIdx.x;
    const long m0 = (long)blockIdx.x * 64;
    const int bb = (int)(m0 >> 12);
    const int tile = (int)((m0 & 4095) >> 6);
    const long img_base = ((long)bb * 64 + tile) * 32768;  // bytes

    const int wave = t >> 6, lane = t & 63;
    const int lr = lane & 15, lh = lane >> 4;

    // weight chunk staging: global -> regs -> swizzled LDS
    short8 wreg[8];
    auto wload = [&](int j) {   // chunk j in 0..11 (z = j>>2, cc = j&3)
        const char* src = (const char*)wt_all + (long)j * 32768 + t * 16;
        #pragma unroll
        for (int i = 0; i < 8; ++i)
            wreg[i] = *reinterpret_cast<const short8*>(src + i * 4096);
    };
    auto wstore = [&]() {
        #pragma unroll
        for (int i = 0; i < 8; ++i) {
            int g = i * 4096 + t * 16;
            int row = g >> 9, slot = (g >> 4) & 31;
            *reinterpret_cast<short8*>(
                wchunk + row * 512 + ((slot ^ (row & 7)) * 16)) = wreg[i];
        }
    };

    wload(0);

    // stage X tile (fp32 -> bf16) into LDS
    #pragma unroll
    for (int i = 0; i < 16; ++i) {
        int idx = i * 256 + t;
        int row = idx >> 6;
        int c4 = (idx & 63) << 2;
        float4 v = *reinterpret_cast<const float4*>(x + (m0 + row) * CDIM + c4);
        ushort4 pk;
        pk.x = f2bf(v.x); pk.y = f2bf(v.y); pk.z = f2bf(v.z); pk.w = f2bf(v.w);
        *reinterpret_cast<ushort4*>(&xs[row * 256 + c4]) = pk;
    }
    __syncthreads();

    short8 a_frag[8];
    #pragma unroll
    for (int kk = 0; kk < 8; ++kk)
        a_frag[kk] = *reinterpret_cast<const short8*>(
            &xs[(wave * 16 + lr) * 256 + kk * 32 + lh * 8]);

    wstore();
    __syncthreads();
    wload(1);

    for (int j = 0; j < 12; ++j) {
        const int z = j >> 2, cc = j & 3;

        f32x4 acc[4];
        #pragma unroll
        for (int cb = 0; cb < 4; ++cb) acc[cb] = (f32x4)(0.0f);

        __builtin_amdgcn_s_setprio(1);
        #pragma unroll
        for (int kk = 0; kk < 8; ++kk) {
            #pragma unroll
            for (int cb = 0; cb < 4; ++cb) {
                short8 b_frag = *reinterpret_cast<const short8*>(
                    wchunk + (cb * 16 + lr) * 512 + (((kk * 4 + lh) ^ (lr & 7)) * 16));
                acc[cb] = mfma32(a_frag[kk], b_frag, acc[cb]);
            }
        }
        __builtin_amdgcn_s_setprio(0);

        if (z < 2) {
            const float* bias = (z == 0) ? bq : bk;
            const float bs = (z == 0) ? 0.0625f * LOG2E : 1.0f;
            #pragma unroll
            for (int cb = 0; cb < 4; ++cb) {
                int c = cc * 64 + cb * 16 + lr;
                float bb_ = bias[c] * bs;
                #pragma unroll
                for (int r = 0; r < 4; ++r)
                    xs[(wave * 16 + lh * 4 + r) * 256 + c] = f2bf(acc[cb][r] + bb_);
            }
        } else {
            char* xc = (char*)xs;
            #pragma unroll
            for (int cb = 0; cb < 4; ++cb) {
                int c = cc * 64 + cb * 16 + lr;
                float bb_ = bv[c];
                #pragma unroll
                for (int r = 0; r < 4; ++r) {
                    int n = wave * 16 + lh * 4 + r;
                    *reinterpret_cast<unsigned short*>(
                        xc + c * 128 + (((n >> 3) ^ (c & 7)) * 16) + (n & 7) * 2)
                        = f2bf(acc[cb][r] + bb_);
                }
            }
        }
        __syncthreads();

        if (cc == 3) {
            if (z == 0) {
                char* dst = (char*)q_ws + m0 * 512;
                const char* src = (const char*)xs;
                #pragma unroll
                for (int i = 0; i < 8; ++i) {
                    int g = i * 4096 + t * 16;
                    *reinterpret_cast<short8*>(dst + g) =
                        *reinterpret_cast<const short8*>(src + g);
                }
            } else if (z == 1) {
                char* dst = (char*)k_img + img_base;
                #pragma unroll
                for (int i = 0; i < 8; ++i) {
                    int g = i * 4096 + t * 16;
                    int row = g >> 9, sp = (g >> 4) & 31;
                    int s = sp ^ (row & 7);
                    *reinterpret_cast<short8*>(dst + g) =
                        *reinterpret_cast<const short8*>(&xs[row * 256 + s * 8]);
                }
            } else {
                char* dst = (char*)v_img + img_base;
                const char* src = (const char*)xs;
                #pragma unroll
                for (int i = 0; i < 8; ++i) {
                    int g = i * 4096 + t * 16;
                    *reinterpret_cast<short8*>(dst + g) =
                        *reinterpret_cast<const short8*>(src + g);
                }
            }
        }

        if (j < 11) wstore();
        if (j < 10) wload(j + 2);
        __syncthreads();
    }
}

// ---------- kernel 3: fused flash attention (32x32 MFMA) + projection + residual ----------
// 256 blocks, 8 waves x 32 q rows. Swapped QK^T via mfma_32x32x16 (lane owns one
// q column), in-register softmax in the exp2 domain, ALL cross-lane traffic via
// v_permlane32_swap (VALU) — zero DS ops in softmax. Full-rate 32x32 PV,
// global_load_lds double-buffered K/V staging.
__global__ __launch_bounds__(512, 2) void attn_kernel(
    const unsigned short* __restrict__ q_ws,
    const unsigned short* __restrict__ k_img,
    const unsigned short* __restrict__ v_img,
    const unsigned short* __restrict__ wpt,
    const float* __restrict__ bp,
    const float* __restrict__ x,
    float* __restrict__ out)
{
    extern __shared__ char smem[];
    char* ksb = smem;             // 2 x 32KB K tiles [64 k][512B], slot ^= row&7
    char* vsb = smem + 65536;     // 2 x 32KB V tiles [256 c][128B], slot ^= c&7
    const int t = threadIdx.x;
    const int wave = t >> 6, lane = t & 63;
    const int q32 = lane & 31;    // lane's q column (and K/V row index)
    const int u   = lane >> 5;
    const int lr = lane & 15, lh = lane >> 4;   // for 16x16 proj epilogue

    // XCD-aware mapping: batch b's 16 blocks all live on XCD b>>1
    const int bid = blockIdx.x;
    const int xcd = bid & 7, ii = bid >> 3;
    const int b = (xcd << 1) | (ii & 1);
    const int qc = ii >> 1;
    const long qbase = (long)b * NTOK + qc * 256 + wave * 32;

    const char* kg = (const char*)k_img + ((long)b * 64) * 32768;
    const char* vg = (const char*)v_img + ((long)b * 64) * 32768;

    // resident Q (B-operand): qf[kk] = Q[qbase+q32][kk*16 + u*8 .. +8], scale folded
    short8 qf[16];
    #pragma unroll
    for (int kk = 0; kk < 16; ++kk)
        qf[kk] = *reinterpret_cast<const short8*>(
            &q_ws[(qbase + q32) * 256 + kk * 16 + u * 8]);

    // acc[cb]: O^T[c = cb*32 + (r&3)+8*(r>>2)+4u][q32]
    f32x16 acc[8];
    #pragma unroll
    for (int cb = 0; cb < 8; ++cb) acc[cb] = (f32x16)(0.0f);
    float m_run = -INFINITY, l_run = 0.f;

    auto stage = [&](int nb, int tt) {
        const char* ks = kg + (long)tt * 32768 + wave * 4096 + lane * 16;
        char* kd = ksb + nb * 32768 + wave * 4096;
        #pragma unroll
        for (int i = 0; i < 4; ++i) ldsdma16(kd + i * 1024, ks + i * 1024);
        const char* vs = vg + (long)tt * 32768 + wave * 4096 + lane * 16;
        char* vd = vsb + nb * 32768 + wave * 4096;
        #pragma unroll
        for (int i = 0; i < 4; ++i) ldsdma16(vd + i * 1024, vs + i * 1024);
    };

    stage(0, 0);
    __syncthreads();

    for (int tt = 0; tt < 64; ++tt) {
        const int buf = tt & 1;
        if (tt < 63) stage(buf ^ 1, tt + 1);   // issue early; barrier drains it
        const char* kb = ksb + buf * 32768;
        const char* vb = vsb + buf * 32768;

        #pragma unroll
        for (int h = 0; h < 2; ++h) {
            // ---- QK^T: S^T[32 k][32 q] in one f32x16 (exp2-domain scores) ----
            f32x16 s = (f32x16)(0.0f);
            __builtin_amdgcn_s_setprio(1);
            #pragma unroll
            for (int kk = 0; kk < 16; ++kk) {
                short8 kf = *reinterpret_cast<const short8*>(
                    kb + (h * 32 + q32) * 512 + (((kk * 2 + u) ^ (q32 & 7)) * 16));
                s = mfma32x32(kf, qf[kk], s);
            }
            __builtin_amdgcn_s_setprio(0);

            // ---- in-register online softmax (lane owns q; 16 k vals + partner) ----
            float mt = fmaxf(fmaxf(fmaxf(s[0], s[1]), fmaxf(s[2], s[3])),
                             fmaxf(fmaxf(s[4], s[5]), fmaxf(s[6], s[7])));
            mt = fmaxf(mt, fmaxf(fmaxf(fmaxf(s[8], s[9]), fmaxf(s[10], s[11])),
                                 fmaxf(fmaxf(s[12], s[13]), fmaxf(s[14], s[15]))));
            mt = xor32_max(mt);
            if (!__all(mt <= m_run + 10.0f)) {    // defer-max (T13, log2 domain)
                float mn = fmaxf(m_run, mt);
                float a = fexp2(m_run - mn);
                l_run *= a;
                #pragma unroll
                for (int cb = 0; cb < 8; ++cb)
                    #pragma unroll
                    for (int r = 0; r < 16; ++r) acc[cb][r] *= a;
                m_run = mn;
            }
            unsigned plo[4], phi[4];
            float rs = 0.f;
            #pragma unroll
            for (int m = 0; m < 4; ++m) {
                float e0 = fexp2(s[4*m+0] - m_run);
                float e1 = fexp2(s[4*m+1] - m_run);
                float e2 = fexp2(s[4*m+2] - m_run);
                float e3 = fexp2(s[4*m+3] - m_run);
                rs += (e0 + e1) + (e2 + e3);
                plo[m] = cvt_pk_bf16(e0, e1);   // k = 8m+4u+0,1
                phi[m] = cvt_pk_bf16(e2, e3);   // k = 8m+4u+2,3
            }
            l_run += xor32_sum(rs);

            // ---- PV: acc[c][q] += V^T[c][k16] @ P^T[k16][q], two K=16 steps ----
            #pragma unroll
            for (int tp = 0; tp < 2; ++tp) {
                // B-frag k = 16*tp + 8u + j. permlane32_swap(a,b) yields
                // a={a.lo,b.lo} (= k-pairs from u=0 lanes), b={a.hi,b.hi} (u=1).
                unsigned a0 = plo[2*tp], b0 = plo[2*tp+1];
                unsigned a1 = phi[2*tp], b1 = phi[2*tp+1];
                permlane32_swap(a0, b0);
                permlane32_swap(a1, b1);
                union { unsigned w[4]; short8 v; } pf;
                pf.w[0] = a0;   // k pair (16tp+8u+0,1)
                pf.w[1] = a1;   // k pair (+2,+3)
                pf.w[2] = b0;   // k pair (+4,+5)
                pf.w[3] = b1;   // k pair (+6,+7)
                __builtin_amdgcn_s_setprio(1);
                #pragma unroll
                for (int cb = 0; cb < 8; ++cb) {
                    int c = cb * 32 + q32;
                    short8 vf = *reinterpret_cast<const short8*>(
                        vb + c * 128 + (((h * 4 + 2 * tp + u) ^ (c & 7)) * 16));
                    acc[cb] = mfma32x32(vf, pf.v, acc[cb]);
                }
                __builtin_amdgcn_s_setprio(0);
            }
        }
        __syncthreads();   // drains DMA for tile tt+1; K/V readers done
    }

    // ---- epilogue: O^T -> per-wave LDS transpose (swizzled, paired b32 writes) ----
    __syncthreads();   // all waves done with ksb/vsb before overwriting with ot
    float inv = 1.0f / l_run;
    char* ot = smem + wave * 16384;   // [32 q][512B], slot ^= q&7
    #pragma unroll
    for (int cb = 0; cb < 8; ++cb) {
        #pragma unroll
        for (int i = 0; i < 8; ++i) {
            int c = cb * 32 + ((2 * i) & 3) + 8 * (i >> 1) + 4 * u;
            unsigned w = cvt_pk_bf16(acc[cb][2*i] * inv, acc[cb][2*i+1] * inv);
            *reinterpret_cast<unsigned*>(
                ot + q32 * 512 + (((c >> 3) ^ (q32 & 7)) * 16) + (c & 7) * 2) = w;
        }
    }

    // ---- fused projection: OUT = O @ Wp + bp + x (16x16x32, per-wave ot) ----
    f32x4 po[2][16];
    #pragma unroll
    for (int qb = 0; qb < 2; ++qb)
        #pragma unroll
        for (int cb = 0; cb < 16; ++cb) po[qb][cb] = (f32x4)(0.0f);

    for (int kk = 0; kk < 8; ++kk) {
        int slot = (kk * 4 + lh);
        short8 a0 = *reinterpret_cast<const short8*>(
            ot + (0 * 16 + lr) * 512 + ((slot ^ (lr & 7)) * 16));
        short8 a1 = *reinterpret_cast<const short8*>(
            ot + (1 * 16 + lr) * 512 + ((slot ^ (lr & 7)) * 16));
        #pragma unroll
        for (int cb = 0; cb < 16; ++cb) {
            short8 bf_ = *reinterpret_cast<const short8*>(
                &wpt[(cb * 16 + lr) * 256 + kk * 32 + lh * 8]);
            po[0][cb] = mfma32(a0, bf_, po[0][cb]);
            po[1][cb] = mfma32(a1, bf_, po[1][cb]);
        }
    }

    #pragma unroll
    for (int qb = 0; qb < 2; ++qb) {
        #pragma unroll
        for (int cb = 0; cb < 16; ++cb) {
            int c = cb * 16 + lr;
            float bias = bp[c];
            #pragma unroll
            for (int r = 0; r < 4; ++r) {
                long row = qbase + qb * 16 + lh * 4 + r;
                out[row * 256 + c] = po[qb][cb][r] + bias + x[row * 256 + c];
            }
        }
    }
}

extern "C" void kernel_launch(void* const* d_in, const int* in_sizes, int n_in,
                              void* d_out, int out_size, void* d_ws, size_t ws_size,
                              hipStream_t stream) {
    const float* x  = (const float*)d_in[0];
    const float* wq = (const float*)d_in[1];
    const float* bq = (const float*)d_in[2];
    const float* wk = (const float*)d_in[3];
    const float* bk = (const float*)d_in[4];
    const float* wv = (const float*)d_in[5];
    const float* bv = (const float*)d_in[6];
    const float* wp = (const float*)d_in[7];
    const float* bp = (const float*)d_in[8];
    float* out = (float*)d_out;

    char* ws = (char*)d_ws;
    unsigned short* wt_all = (unsigned short*)ws;               // 512 KiB
    unsigned short* q_ws   = (unsigned short*)(ws + 524288);    // 32 MiB
    unsigned short* k_img  = q_ws + (size_t)MROWS * CDIM;       // 32 MiB
    unsigned short* v_img  = k_img + (size_t)MROWS * CDIM;      // 32 MiB

    prep_w_kernel<<<dim3(256, 4), 256, 0, stream>>>(wq, wk, wv, wp, wt_all);
    qkv_kernel<<<dim3(MROWS / 64), 256, 0, stream>>>(x, wt_all, bq, bk, bv,
                                                     q_ws, k_img, v_img);
    hipFuncSetAttribute((const void*)attn_kernel,
                        hipFuncAttributeMaxDynamicSharedMemorySize, 131072);
    attn_kernel<<<dim3(256), 512, 131072, stream>>>(q_ws, k_img, v_img,
                                                    wt_all + 3 * 65536, bp, x, out);
}